// Round 1
// baseline (101.332 us; speedup 1.0000x reference)
//
#include <hip/hip_runtime.h>
#include <math.h>

#define NB 8
#define NC 16
#define SIDE 64
#define CELLS 512            // 8^3
#define HALF 4096            // NB*CELLS
#define NROWS 8192           // 2*HALF
#define NCHUNK 64
#define CHUNKJ 128           // NROWS / NCHUNK
#define INV_TEMP 10.0f

// ---------------------------------------------------------------- pooling
// One thread per pooled output scalar (p, b, c, cell). 131072 threads.
__global__ __launch_bounds__(256) void pool_kernel(const float* __restrict__ p1,
                                                   const float* __restrict__ p2,
                                                   float* __restrict__ mm) {
    int flat = blockIdx.x * 256 + threadIdx.x;      // 0..131071
    int p    = flat >> 16;                          // view index (uniform per block)
    int rem  = flat & 65535;
    int b    = rem >> 13;
    int rem2 = rem & 8191;
    int c    = rem2 >> 9;
    int cell = rem2 & 511;
    int zb = cell >> 6;
    int yb = (cell >> 3) & 7;
    int xb = cell & 7;
    const float* src  = p ? p2 : p1;
    const float* base = src + ((((size_t)(b * NC + c) * SIDE + zb * 8) * SIDE + yb * 8) * SIDE + xb * 8);
    float acc = 0.f;
    for (int dz = 0; dz < 8; ++dz) {
        #pragma unroll
        for (int dy = 0; dy < 8; ++dy) {
            const float4* q = (const float4*)(base + dz * 4096 + dy * 64);
            float4 v0 = q[0];
            float4 v1 = q[1];
            acc += (v0.x + v0.y) + (v0.z + v0.w) + (v1.x + v1.y) + (v1.z + v1.w);
        }
    }
    int row = p * HALF + b * CELLS + cell;          // matches reshape->transpose order
    mm[row * NC + c] = acc * (1.0f / 512.0f);
}

// ---------------------------------------------------------------- MLP + normalize
__global__ __launch_bounds__(256) void mlp_kernel(const float* __restrict__ mm,
                                                  const float* __restrict__ w1,
                                                  const float* __restrict__ b1,
                                                  const float* __restrict__ w2,
                                                  const float* __restrict__ b2,
                                                  float* __restrict__ f) {
    __shared__ float sw1[256], sw2[256], sb1[16], sb2[16];
    int t = threadIdx.x;
    sw1[t] = w1[t];
    sw2[t] = w2[t];
    if (t < 16) { sb1[t] = b1[t]; sb2[t] = b2[t]; }
    __syncthreads();
    int row = blockIdx.x * 256 + t;
    float x[16];
    const float4* src = (const float4*)(mm + row * NC);
    #pragma unroll
    for (int i = 0; i < 4; ++i) {
        float4 v = src[i];
        x[i*4+0]=v.x; x[i*4+1]=v.y; x[i*4+2]=v.z; x[i*4+3]=v.w;
    }
    float h[16];
    #pragma unroll
    for (int i = 0; i < 16; ++i) {
        float a = sb1[i];
        #pragma unroll
        for (int k = 0; k < 16; ++k) a = fmaf(x[k], sw1[i*16+k], a);
        h[i] = a > 0.f ? a : 0.f;
    }
    float ff[16];
    float nrm = 0.f;
    #pragma unroll
    for (int i = 0; i < 16; ++i) {
        float a = sb2[i];
        #pragma unroll
        for (int k = 0; k < 16; ++k) a = fmaf(h[k], sw2[i*16+k], a);
        ff[i] = a;
        nrm = fmaf(a, a, nrm);
    }
    float inv = 1.0f / fmaxf(sqrtf(nrm), 1e-12f);
    float4* dst = (float4*)(f + row * NC);
    #pragma unroll
    for (int i = 0; i < 4; ++i) {
        float4 v;
        v.x = ff[i*4+0]*inv; v.y = ff[i*4+1]*inv; v.z = ff[i*4+2]*inv; v.w = ff[i*4+3]*inv;
        dst[i] = v;
    }
}

// ---------------------------------------------------------------- logits + partial expsum
// block = (row-block rb of 1024 rows) x (j-chunk ck of 128 cols); 512 blocks x 256 thr.
// Each thread owns 4 rows, iterates its chunk's 128 j's staged in LDS (broadcast reads).
__global__ __launch_bounds__(256) void lse_partial(const float* __restrict__ f,
                                                   float* __restrict__ partial,
                                                   float* __restrict__ pos) {
    __shared__ float tile[CHUNKJ * NC];             // 8 KB
    int rb = blockIdx.x >> 6;
    int ck = blockIdx.x & 63;
    int t  = threadIdx.x;
    int jbase = ck * CHUNKJ;
    {
        const float4* fsrc = (const float4*)(f + (size_t)jbase * NC);
        float4* tdst = (float4*)tile;
        tdst[t]       = fsrc[t];
        tdst[t + 256] = fsrc[t + 256];
    }
    __syncthreads();
    int r0 = rb * 1024 + t * 4;
    float fi[4][16];
    #pragma unroll
    for (int rr = 0; rr < 4; ++rr) {
        const float4* q = (const float4*)(f + (size_t)(r0 + rr) * NC);
        #pragma unroll
        for (int i = 0; i < 4; ++i) {
            float4 v = q[i];
            fi[rr][i*4+0]=v.x; fi[rr][i*4+1]=v.y; fi[rr][i*4+2]=v.z; fi[rr][i*4+3]=v.w;
        }
    }
    float s[4]  = {0.f, 0.f, 0.f, 0.f};
    float pv[4] = {0.f, 0.f, 0.f, 0.f};
    int pr[4];
    #pragma unroll
    for (int rr = 0; rr < 4; ++rr) pr[rr] = (r0 + rr + HALF) & (NROWS - 1);

    for (int jj = 0; jj < CHUNKJ; ++jj) {
        float fj[16];
        const float4* tj = (const float4*)(tile + jj * NC);
        #pragma unroll
        for (int i = 0; i < 4; ++i) {
            float4 v = tj[i];
            fj[i*4+0]=v.x; fj[i*4+1]=v.y; fj[i*4+2]=v.z; fj[i*4+3]=v.w;
        }
        int j = jbase + jj;
        #pragma unroll
        for (int rr = 0; rr < 4; ++rr) {
            float d = 0.f;
            #pragma unroll
            for (int k = 0; k < 16; ++k) d = fmaf(fi[rr][k], fj[k], d);
            float l = d * INV_TEMP;
            float e = __expf(l - INV_TEMP);          // fixed shift: max logit = 10
            s[rr] += (j == r0 + rr) ? 0.f : e;       // mask diagonal
            pv[rr] = (j == pr[rr]) ? l : pv[rr];     // capture positive
        }
    }
    #pragma unroll
    for (int rr = 0; rr < 4; ++rr) {
        int r = r0 + rr;
        partial[(size_t)r * NCHUNK + ck] = s[rr];
        if (pr[rr] >= jbase && pr[rr] < jbase + CHUNKJ) pos[r] = pv[rr];
    }
}

// ---------------------------------------------------------------- per-row lse + block sums
__global__ __launch_bounds__(256) void lse_finish(const float* __restrict__ partial,
                                                  const float* __restrict__ pos,
                                                  float* __restrict__ bsum) {
    int r = blockIdx.x * 256 + threadIdx.x;
    const float4* q = (const float4*)(partial + (size_t)r * NCHUNK);
    float s = 0.f;
    #pragma unroll
    for (int i = 0; i < 16; ++i) {
        float4 v = q[i];
        s += (v.x + v.y) + (v.z + v.w);
    }
    float val = (logf(s) + INV_TEMP) - pos[r];
    __shared__ float red[256];
    red[threadIdx.x] = val;
    __syncthreads();
    for (int off = 128; off > 0; off >>= 1) {
        if (threadIdx.x < off) red[threadIdx.x] += red[threadIdx.x + off];
        __syncthreads();
    }
    if (threadIdx.x == 0) bsum[blockIdx.x] = red[0];
}

__global__ void final_mean(const float* __restrict__ bsum, float* __restrict__ out) {
    if (threadIdx.x == 0) {
        float s = 0.f;
        for (int i = 0; i < 32; ++i) s += bsum[i];
        out[0] = s * (1.0f / (float)NROWS);
    }
}

// ---------------------------------------------------------------- launch
extern "C" void kernel_launch(void* const* d_in, const int* in_sizes, int n_in,
                              void* d_out, int out_size, void* d_ws, size_t ws_size,
                              hipStream_t stream) {
    const float* p1 = (const float*)d_in[0];
    const float* p2 = (const float*)d_in[1];
    const float* w1 = (const float*)d_in[2];
    const float* b1 = (const float*)d_in[3];
    const float* w2 = (const float*)d_in[4];
    const float* b2 = (const float*)d_in[5];
    float* out = (float*)d_out;

    char* ws = (char*)d_ws;
    float* mm      = (float*)(ws);                          // 512 KB
    float* f       = (float*)(ws + 512 * 1024);             // 512 KB
    float* partial = (float*)(ws + 1024 * 1024);            // 2 MB
    float* pos     = (float*)(ws + 3 * 1024 * 1024);        // 32 KB
    float* bsum    = (float*)(ws + 3 * 1024 * 1024 + 64 * 1024); // 128 B

    hipLaunchKernelGGL(pool_kernel, dim3(512), dim3(256), 0, stream, p1, p2, mm);
    hipLaunchKernelGGL(mlp_kernel,  dim3(32),  dim3(256), 0, stream, mm, w1, b1, w2, b2, f);
    hipLaunchKernelGGL(lse_partial, dim3(512), dim3(256), 0, stream, f, partial, pos);
    hipLaunchKernelGGL(lse_finish,  dim3(32),  dim3(256), 0, stream, partial, pos, bsum);
    hipLaunchKernelGGL(final_mean,  dim3(1),   dim3(64),  0, stream, bsum, out);
}